// Round 9
// baseline (374.814 us; speedup 1.0000x reference)
//
#include <hip/hip_runtime.h>
#include <hip/hip_bf16.h>

typedef __attribute__((ext_vector_type(8))) short s16x8;
typedef __attribute__((ext_vector_type(4))) float f32x4;

#define HC 48       // edge chunks (hist + scatter)
#define RBH 6400    // hist bins per range (25.6 KB LDS, 16 ranges for N=100k)
#define RBS 3200    // scatter cursors per range (12.8 KB LDS, 32 ranges)

static __device__ __forceinline__ unsigned short f2bf(float f) {
    unsigned int u = __float_as_uint(f);
    unsigned int r = (u + 0x7FFFu + ((u >> 16) & 1u)) >> 16;
    return (unsigned short)r;
}

// ---- partial histograms (ushort out), zero global atomics, int4 edge loads ----
__global__ __launch_bounds__(256) void k_hist(const int* __restrict__ eidx,
                                              unsigned short* __restrict__ partials,
                                              int N, int E, int HR) {
    __shared__ int h[RBH];
    int b = blockIdx.x;
    int job = b / (HR * HC);
    int rc = b % (HR * HC);
    int r = rc / HC, c = rc % HC;
    int lo = r * RBH;
    int nb = min(RBH, N - lo);
    if (nb <= 0) return;
    for (int i = threadIdx.x; i < nb; i += 256) h[i] = 0;
    __syncthreads();
    const int* vals = eidx + (size_t)job * E;
    int e0 = (int)(((long long)E * c / HC) & ~3LL);
    int e1 = (c == HC - 1) ? E : (int)(((long long)E * (c + 1) / HC) & ~3LL);
    int e = e0 + threadIdx.x * 4;
    for (; e + 4 <= e1; e += 1024) {
        int4 v = *reinterpret_cast<const int4*>(vals + e);
        unsigned r0 = (unsigned)(v.x - lo), r1 = (unsigned)(v.y - lo);
        unsigned r2 = (unsigned)(v.z - lo), r3 = (unsigned)(v.w - lo);
        if (r0 < (unsigned)nb) atomicAdd(&h[r0], 1);
        if (r1 < (unsigned)nb) atomicAdd(&h[r1], 1);
        if (r2 < (unsigned)nb) atomicAdd(&h[r2], 1);
        if (r3 < (unsigned)nb) atomicAdd(&h[r3], 1);
    }
    if (threadIdx.x == 0)
        for (int t = e1 & ~3; t < e1; ++t) {
            unsigned rel = (unsigned)(vals[t] - lo);
            if (rel < (unsigned)nb) atomicAdd(&h[rel], 1);
        }
    __syncthreads();
    unsigned short* outp = partials + ((size_t)(job * HC + c)) * N + lo;
    for (int i = threadIdx.x; i < nb; i += 256) outp[i] = (unsigned short)h[i];
}

// ---- combine partials -> dis (rsqrt of src-degree) and cnt (dst histogram) ----
__global__ void k_reduce(const unsigned short* __restrict__ partials,
                         float* __restrict__ dis, int* __restrict__ cnt, int N) {
    int n = blockIdx.x * blockDim.x + threadIdx.x;
    if (n >= N) return;
    int dsum = 0, csum = 0;
    for (int c = 0; c < HC; ++c) {
        dsum += partials[(size_t)c * N + n];
        csum += partials[(size_t)(HC + c) * N + n];
    }
    dis[n] = dsum > 0 ? rsqrtf((float)dsum) : 0.f;
    cnt[n] = csum;
}

// ---- scan of cnt -> rowptr ----
__global__ void k_scan1(const int* __restrict__ cnt, int* __restrict__ incl,
                        int* __restrict__ bsum, int N) {
    __shared__ int sm[1024];
    int t = threadIdx.x;
    int i = blockIdx.x * 1024 + t;
    sm[t] = (i < N) ? cnt[i] : 0;
    __syncthreads();
    for (int off = 1; off < 1024; off <<= 1) {
        int add = (t >= off) ? sm[t - off] : 0;
        __syncthreads();
        sm[t] += add;
        __syncthreads();
    }
    if (i < N) incl[i] = sm[t];
    if (t == 1023) bsum[blockIdx.x] = sm[1023];
}

__global__ void k_scan2(const int* __restrict__ bsum, int* __restrict__ boff,
                        int nb, int* __restrict__ rowptr, int N) {
    if (threadIdx.x == 0 && blockIdx.x == 0) {
        int run = 0;
        for (int b = 0; b < nb; ++b) { boff[b] = run; run += bsum[b]; }
        rowptr[N] = run;
    }
}

// ---- scan finalize + per-chunk cursor bases ----
__global__ void k_scan3(const int* __restrict__ cnt, const int* __restrict__ boff,
                        int* __restrict__ rowptr,
                        const unsigned short* __restrict__ pdst,
                        int* __restrict__ cbase, int N) {
    int i = blockIdx.x * 1024 + threadIdx.x;
    if (i >= N) return;
    int ex = rowptr[i] - cnt[i] + boff[blockIdx.x];
    rowptr[i] = ex;
    int run = ex;
    for (int c = 0; c < HC; ++c) {
        size_t idx = (size_t)c * N + i;
        cbase[idx] = run;
        run += pdst[idx];
    }
}

// ---- bucket edges by dst: srcs[p] = src (4 B payload, LDS cursors, int4 loads) ----
__global__ __launch_bounds__(256) void k_scatter(
        const int* __restrict__ src, const int* __restrict__ dst,
        const int* __restrict__ cbase, int* __restrict__ srcs, int N, int E) {
    __shared__ int cur[RBS];
    int r = blockIdx.x / HC, c = blockIdx.x % HC;
    int lo = r * RBS;
    int nb = min(RBS, N - lo);
    if (nb <= 0) return;
    for (int i = threadIdx.x; i < nb; i += 256)
        cur[i] = cbase[(size_t)c * N + lo + i];
    __syncthreads();
    int e0 = (int)(((long long)E * c / HC) & ~3LL);
    int e1 = (c == HC - 1) ? E : (int)(((long long)E * (c + 1) / HC) & ~3LL);
    int e = e0 + threadIdx.x * 4;
    for (; e + 4 <= e1; e += 1024) {
        int4 d4 = *reinterpret_cast<const int4*>(dst + e);
        unsigned r0 = (unsigned)(d4.x - lo), r1 = (unsigned)(d4.y - lo);
        unsigned r2 = (unsigned)(d4.z - lo), r3 = (unsigned)(d4.w - lo);
        if (r0 < (unsigned)nb) srcs[atomicAdd(&cur[r0], 1)] = src[e];
        if (r1 < (unsigned)nb) srcs[atomicAdd(&cur[r1], 1)] = src[e + 1];
        if (r2 < (unsigned)nb) srcs[atomicAdd(&cur[r2], 1)] = src[e + 2];
        if (r3 < (unsigned)nb) srcs[atomicAdd(&cur[r3], 1)] = src[e + 3];
    }
    if (threadIdx.x == 0)
        for (int t = e1 & ~3; t < e1; ++t) {
            unsigned rel = (unsigned)(dst[t] - lo);
            if (rel < (unsigned)nb) srcs[atomicAdd(&cur[rel], 1)] = src[t];
        }
}

// ---- merged pack: T0 = bf16(x); Ys0 = bf16(dis*x); pad rows; Wt transpose ----
__global__ void k_pack(const float* __restrict__ x, const float* __restrict__ dis,
                       const float* __restrict__ W,
                       unsigned short* __restrict__ tb0, unsigned short* __restrict__ ysA,
                       unsigned short* __restrict__ ysB, unsigned short* __restrict__ wt,
                       int N, int K) {
    int t = blockIdx.x * blockDim.x + threadIdx.x;
    int nys = (N + 1) * 32;
    if (t < nys) {
        int row = t >> 5, p = t & 31;
        size_t o = ((size_t)row << 6) + (p << 1);
        if (row == N) {
            *(unsigned*)(ysA + o) = 0;
            *(unsigned*)(ysB + o) = 0;
            return;
        }
        float2 v = *reinterpret_cast<const float2*>(x + o);
        float dv = dis[row];
        *(unsigned*)(tb0 + o) = (unsigned)f2bf(v.x) | ((unsigned)f2bf(v.y) << 16);
        *(unsigned*)(ysA + o) = (unsigned)f2bf(v.x * dv) | ((unsigned)f2bf(v.y * dv) << 16);
    } else {
        int u = t - nys;
        if (u < K * 4096) {
            float v = W[u];
            int k = u >> 12;
            int r = u & 4095;
            int i = r >> 6;
            int j = r & 63;
            wt[(size_t)j * (K * 64) + (k << 6) + i] = f2bf(v);
        }
    }
}

static __device__ __forceinline__ void addrow(float* acc, uint4 t) {
    acc[0] += __uint_as_float(t.x << 16);
    acc[1] += __uint_as_float(t.x & 0xffff0000u);
    acc[2] += __uint_as_float(t.y << 16);
    acc[3] += __uint_as_float(t.y & 0xffff0000u);
    acc[4] += __uint_as_float(t.z << 16);
    acc[5] += __uint_as_float(t.z & 0xffff0000u);
    acc[6] += __uint_as_float(t.w << 16);
    acc[7] += __uint_as_float(t.w & 0xffff0000u);
}

// ---- Chebyshev propagation, slot-per-node, 8 edges in flight per slot ----
__global__ __launch_bounds__(256) void k_prop(
        const unsigned short* __restrict__ Ysin,
        const unsigned short* __restrict__ Tm2,
        unsigned short* __restrict__ Tout,
        unsigned short* __restrict__ Ysout,
        const int* __restrict__ rowptr, const int* __restrict__ srcs,
        const float* __restrict__ dis,
        int N, int E, float scale, float beta, int wys) {
    int gt = blockIdx.x * blockDim.x + threadIdx.x;
    int wave0 = (gt >> 6) << 3;          // first node of this wave
    int lane = gt & 63;
    int g = lane >> 3;                   // slot -> node wave0+g
    int i = lane & 7;                    // feature octet
    int node = wave0 + g;
    bool live = node < N;
    int rs = 0, deg = 0;
    if (live) {
        rs = rowptr[node];
        deg = rowptr[node + 1] - rs;
    }
    int wmax = deg;
#pragma unroll
    for (int m = 8; m <= 32; m <<= 1) {
        int o = __shfl_xor(wmax, m);
        wmax = o > wmax ? o : wmax;
    }
    float acc[8];
#pragma unroll
    for (int j = 0; j < 8; ++j) acc[j] = 0.f;
    for (int e = 0; e < wmax; e += 8) {
        int b = rs + e;
        int s[8];
#pragma unroll
        for (int q = 0; q < 8; ++q)
            s[q] = (e + q < deg) ? srcs[min(b + q, E - 1)] : N;
        uint4 t[8];
#pragma unroll
        for (int q = 0; q < 8; ++q)
            t[q] = *reinterpret_cast<const uint4*>(Ysin + ((size_t)s[q] << 6) + (i << 3));
#pragma unroll
        for (int q = 0; q < 8; ++q) addrow(acc, t[q]);
    }
    if (live) {
        float dv = dis[node];
        float sc = -scale * dv;
        size_t base = ((size_t)node << 6) + (i << 3);
        float r[8];
#pragma unroll
        for (int j = 0; j < 8; ++j) r[j] = sc * acc[j];
        if (beta != 0.f) {
            uint4 pv = *reinterpret_cast<const uint4*>(Tm2 + base);
            r[0] = fmaf(beta, __uint_as_float(pv.x << 16), r[0]);
            r[1] = fmaf(beta, __uint_as_float(pv.x & 0xffff0000u), r[1]);
            r[2] = fmaf(beta, __uint_as_float(pv.y << 16), r[2]);
            r[3] = fmaf(beta, __uint_as_float(pv.y & 0xffff0000u), r[3]);
            r[4] = fmaf(beta, __uint_as_float(pv.z << 16), r[4]);
            r[5] = fmaf(beta, __uint_as_float(pv.z & 0xffff0000u), r[5]);
            r[6] = fmaf(beta, __uint_as_float(pv.w << 16), r[6]);
            r[7] = fmaf(beta, __uint_as_float(pv.w & 0xffff0000u), r[7]);
        }
        uint4 ov;
        ov.x = (unsigned)f2bf(r[0]) | ((unsigned)f2bf(r[1]) << 16);
        ov.y = (unsigned)f2bf(r[2]) | ((unsigned)f2bf(r[3]) << 16);
        ov.z = (unsigned)f2bf(r[4]) | ((unsigned)f2bf(r[5]) << 16);
        ov.w = (unsigned)f2bf(r[6]) | ((unsigned)f2bf(r[7]) << 16);
        *reinterpret_cast<uint4*>(Tout + base) = ov;
        if (wys) {
            uint4 yv;
            yv.x = (unsigned)f2bf(r[0] * dv) | ((unsigned)f2bf(r[1] * dv) << 16);
            yv.y = (unsigned)f2bf(r[2] * dv) | ((unsigned)f2bf(r[3] * dv) << 16);
            yv.z = (unsigned)f2bf(r[4] * dv) | ((unsigned)f2bf(r[5] * dv) << 16);
            yv.w = (unsigned)f2bf(r[6] * dv) | ((unsigned)f2bf(r[7] * dv) << 16);
            *reinterpret_cast<uint4*>(Ysout + base) = yv;
        }
    }
}

// ---- out = relu( sum_k T_k @ W_k + bias ) via D = W^T . T^T (MFMA 16x16x32 bf16)
// Explicit load phase: bf[KS] live array forces ~64 VGPRs of B-frags so all
// KS loads are in flight before one vmcnt drain (R8: VGPR=44 => serialized).
template <int KS>
__global__ __launch_bounds__(256, 4) void k_gemm(const unsigned short* __restrict__ tb,
                                                 const unsigned short* __restrict__ wt,
                                                 const float* __restrict__ bias,
                                                 float* __restrict__ out,
                                                 int N, int NF) {
    int lane = threadIdx.x & 63;
    int w = threadIdx.x >> 6;
    int l16 = lane & 15;
    int quad = lane >> 4;
    const int KI = KS * 32;

    s16x8 afr[KS];
    {
        const unsigned short* wrow = wt + (size_t)(w * 16 + l16) * KI + quad * 8;
#pragma unroll
        for (int ks = 0; ks < KS; ++ks)
            afr[ks] = *reinterpret_cast<const s16x8*>(wrow + ks * 32);
    }
    f32x4 bias4 = *reinterpret_cast<const f32x4*>(bias + w * 16 + quad * 4);

    int ntiles = N >> 4;
    for (int t = blockIdx.x; t < ntiles; t += gridDim.x) {
        const unsigned short* bbase = tb + (size_t)(t * 16 + l16) * 64 + quad * 8;
        s16x8 bf[KS];
#pragma unroll
        for (int ks = 0; ks < KS; ++ks)
            bf[ks] = *reinterpret_cast<const s16x8*>(
                bbase + (size_t)(ks >> 1) * NF + (ks & 1) * 32);
        f32x4 acc = {0.f, 0.f, 0.f, 0.f};
#pragma unroll
        for (int ks = 0; ks < KS; ++ks)
            acc = __builtin_amdgcn_mfma_f32_16x16x32_bf16(afr[ks], bf[ks], acc, 0, 0, 0);
        float* orow = out + (size_t)(t * 16 + l16) * 64 + w * 16 + quad * 4;
        f32x4 r;
#pragma unroll
        for (int q = 0; q < 4; ++q) {
            float v = acc[q] + bias4[q];
            r[q] = v > 0.f ? v : 0.f;
        }
        *reinterpret_cast<f32x4*>(orow) = r;
    }
}

extern "C" void kernel_launch(void* const* d_in, const int* in_sizes, int n_in,
                              void* d_out, int out_size, void* d_ws, size_t ws_size,
                              hipStream_t stream) {
    const float* x    = (const float*)d_in[0];
    const int*   eidx = (const int*)d_in[1];
    const float* W    = (const float*)d_in[2];
    const float* bias = (const float*)d_in[3];
    float* out = (float*)d_out;

    const int NF = in_sizes[0];       // N*64
    const int N  = NF / 64;
    const int E  = in_sizes[1] / 2;
    const int K  = in_sizes[2] / 4096;

    const int* src = eidx;
    const int* dst = eidx + E;

    char* ws = (char*)d_ws;
    size_t off = 0;
    auto alloc = [&](size_t bytes) -> char* {
        char* p = ws + off;
        off = (off + bytes + 255) & ~(size_t)255;
        return p;
    };
    unsigned short* Tb = (unsigned short*)alloc((size_t)K * NF * 2);   // bf16 T_0..T_{K-1}
    unsigned short* Ys[2];
    Ys[0] = (unsigned short*)alloc((size_t)(N + 1) * 64 * 2);
    Ys[1] = (unsigned short*)alloc((size_t)(N + 1) * 64 * 2);
    unsigned short* Wt = (unsigned short*)alloc((size_t)64 * K * 64 * 2);
    int*   srcs   = (int*)alloc((size_t)E * 4);
    int*   rowptr = (int*)alloc((size_t)(N + 1) * 4);
    int*   cnt    = (int*)alloc((size_t)N * 4);
    unsigned short* partials = (unsigned short*)alloc((size_t)2 * HC * N * 2);
    int*   cbase  = (int*)alloc((size_t)HC * N * 4);
    float* dis  = (float*)alloc((size_t)N * 4);
    int*   bsum = (int*)alloc(1024);
    int*   boff = (int*)alloc(1024);
    (void)ws_size; (void)n_in; (void)out_size;

    int HR = (N + RBH - 1) / RBH;   // 16
    int SR = (N + RBS - 1) / RBS;   // 32
    const unsigned short* pdst = partials + (size_t)HC * N;

    k_hist<<<2 * HR * HC, 256, 0, stream>>>(eidx, partials, N, E, HR);
    k_reduce<<<(N + 255) / 256, 256, 0, stream>>>(partials, dis, cnt, N);
    int nb = (N + 1023) / 1024;
    k_scan1<<<nb, 1024, 0, stream>>>(cnt, rowptr, bsum, N);
    k_scan2<<<1, 64, 0, stream>>>(bsum, boff, nb, rowptr, N);
    k_scan3<<<nb, 1024, 0, stream>>>(cnt, boff, rowptr, pdst, cbase, N);
    k_scatter<<<SR * HC, 256, 0, stream>>>(src, dst, cbase, srcs, N, E);
    int packn = (N + 1) * 32 + K * 4096;
    k_pack<<<(packn + 255) / 256, 256, 0, stream>>>(x, dis, W, Tb, Ys[0], Ys[1], Wt, N, K);

    // prop grid: 8 nodes per wave
    int waves = (N + 7) / 8;
    int pblocks = (waves * 64 + 255) / 256;
    for (int p = 1; p < K; ++p) {
        float scale = (p == 1) ? 1.f : 2.f;
        float beta  = (p == 1) ? 0.f : -1.f;
        const unsigned short* Tm2 = Tb + (size_t)(p >= 2 ? p - 2 : 0) * NF;
        k_prop<<<pblocks, 256, 0, stream>>>(
            Ys[(p - 1) & 1], Tm2, Tb + (size_t)p * NF, Ys[p & 1],
            rowptr, srcs, dis, N, E, scale, beta, p < K - 1 ? 1 : 0);
    }

    if (K == 8)      k_gemm<16><<<1024, 256, 0, stream>>>(Tb, Wt, bias, out, N, NF);
    else if (K == 4) k_gemm<8><<<1024, 256, 0, stream>>>(Tb, Wt, bias, out, N, NF);
    else if (K == 2) k_gemm<4><<<1024, 256, 0, stream>>>(Tb, Wt, bias, out, N, NF);
    else if (K == 1) k_gemm<2><<<1024, 256, 0, stream>>>(Tb, Wt, bias, out, N, NF);
}

// Round 10
// 342.425 us; speedup vs baseline: 1.0946x; 1.0946x over previous
//
#include <hip/hip_runtime.h>
#include <hip/hip_bf16.h>

typedef __attribute__((ext_vector_type(8))) short s16x8;
typedef __attribute__((ext_vector_type(4))) float f32x4;

#define HC 48       // edge chunks (hist + scatter)
#define RBH 6400    // hist bins per range (25.6 KB LDS, 16 ranges for N=100k)
#define RBS 3200    // scatter cursors per range (12.8 KB LDS, 32 ranges)

static __device__ __forceinline__ unsigned short f2bf(float f) {
    unsigned int u = __float_as_uint(f);
    unsigned int r = (u + 0x7FFFu + ((u >> 16) & 1u)) >> 16;
    return (unsigned short)r;
}

// ---- partial histograms (ushort out), zero global atomics, int4 edge loads ----
__global__ __launch_bounds__(256) void k_hist(const int* __restrict__ eidx,
                                              unsigned short* __restrict__ partials,
                                              int N, int E, int HR) {
    __shared__ int h[RBH];
    int b = blockIdx.x;
    int job = b / (HR * HC);
    int rc = b % (HR * HC);
    int r = rc / HC, c = rc % HC;
    int lo = r * RBH;
    int nb = min(RBH, N - lo);
    if (nb <= 0) return;
    for (int i = threadIdx.x; i < nb; i += 256) h[i] = 0;
    __syncthreads();
    const int* vals = eidx + (size_t)job * E;
    int e0 = (int)(((long long)E * c / HC) & ~3LL);
    int e1 = (c == HC - 1) ? E : (int)(((long long)E * (c + 1) / HC) & ~3LL);
    int e = e0 + threadIdx.x * 4;
    for (; e + 4 <= e1; e += 1024) {
        int4 v = *reinterpret_cast<const int4*>(vals + e);
        unsigned r0 = (unsigned)(v.x - lo), r1 = (unsigned)(v.y - lo);
        unsigned r2 = (unsigned)(v.z - lo), r3 = (unsigned)(v.w - lo);
        if (r0 < (unsigned)nb) atomicAdd(&h[r0], 1);
        if (r1 < (unsigned)nb) atomicAdd(&h[r1], 1);
        if (r2 < (unsigned)nb) atomicAdd(&h[r2], 1);
        if (r3 < (unsigned)nb) atomicAdd(&h[r3], 1);
    }
    if (threadIdx.x == 0)
        for (int t = e1 & ~3; t < e1; ++t) {
            unsigned rel = (unsigned)(vals[t] - lo);
            if (rel < (unsigned)nb) atomicAdd(&h[rel], 1);
        }
    __syncthreads();
    unsigned short* outp = partials + ((size_t)(job * HC + c)) * N + lo;
    for (int i = threadIdx.x; i < nb; i += 256) outp[i] = (unsigned short)h[i];
}

// ---- combine partials -> dis (rsqrt of src-degree) and cnt (dst histogram) ----
__global__ void k_reduce(const unsigned short* __restrict__ partials,
                         float* __restrict__ dis, int* __restrict__ cnt, int N) {
    int n = blockIdx.x * blockDim.x + threadIdx.x;
    if (n >= N) return;
    int dsum = 0, csum = 0;
    for (int c = 0; c < HC; ++c) {
        dsum += partials[(size_t)c * N + n];
        csum += partials[(size_t)(HC + c) * N + n];
    }
    dis[n] = dsum > 0 ? rsqrtf((float)dsum) : 0.f;
    cnt[n] = csum;
}

// ---- scan of cnt -> rowptr ----
__global__ void k_scan1(const int* __restrict__ cnt, int* __restrict__ incl,
                        int* __restrict__ bsum, int N) {
    __shared__ int sm[1024];
    int t = threadIdx.x;
    int i = blockIdx.x * 1024 + t;
    sm[t] = (i < N) ? cnt[i] : 0;
    __syncthreads();
    for (int off = 1; off < 1024; off <<= 1) {
        int add = (t >= off) ? sm[t - off] : 0;
        __syncthreads();
        sm[t] += add;
        __syncthreads();
    }
    if (i < N) incl[i] = sm[t];
    if (t == 1023) bsum[blockIdx.x] = sm[1023];
}

__global__ void k_scan2(const int* __restrict__ bsum, int* __restrict__ boff,
                        int nb, int* __restrict__ rowptr, int N) {
    if (threadIdx.x == 0 && blockIdx.x == 0) {
        int run = 0;
        for (int b = 0; b < nb; ++b) { boff[b] = run; run += bsum[b]; }
        rowptr[N] = run;
    }
}

// ---- scan finalize + per-chunk cursor bases ----
__global__ void k_scan3(const int* __restrict__ cnt, const int* __restrict__ boff,
                        int* __restrict__ rowptr,
                        const unsigned short* __restrict__ pdst,
                        int* __restrict__ cbase, int N) {
    int i = blockIdx.x * 1024 + threadIdx.x;
    if (i >= N) return;
    int ex = rowptr[i] - cnt[i] + boff[blockIdx.x];
    rowptr[i] = ex;
    int run = ex;
    for (int c = 0; c < HC; ++c) {
        size_t idx = (size_t)c * N + i;
        cbase[idx] = run;
        run += pdst[idx];
    }
}

// ---- bucket edges by dst: srcs[p] = src (4 B payload, LDS cursors, int4 loads) ----
__global__ __launch_bounds__(256) void k_scatter(
        const int* __restrict__ src, const int* __restrict__ dst,
        const int* __restrict__ cbase, int* __restrict__ srcs, int N, int E) {
    __shared__ int cur[RBS];
    int r = blockIdx.x / HC, c = blockIdx.x % HC;
    int lo = r * RBS;
    int nb = min(RBS, N - lo);
    if (nb <= 0) return;
    for (int i = threadIdx.x; i < nb; i += 256)
        cur[i] = cbase[(size_t)c * N + lo + i];
    __syncthreads();
    int e0 = (int)(((long long)E * c / HC) & ~3LL);
    int e1 = (c == HC - 1) ? E : (int)(((long long)E * (c + 1) / HC) & ~3LL);
    int e = e0 + threadIdx.x * 4;
    for (; e + 4 <= e1; e += 1024) {
        int4 d4 = *reinterpret_cast<const int4*>(dst + e);
        unsigned r0 = (unsigned)(d4.x - lo), r1 = (unsigned)(d4.y - lo);
        unsigned r2 = (unsigned)(d4.z - lo), r3 = (unsigned)(d4.w - lo);
        if (r0 < (unsigned)nb) srcs[atomicAdd(&cur[r0], 1)] = src[e];
        if (r1 < (unsigned)nb) srcs[atomicAdd(&cur[r1], 1)] = src[e + 1];
        if (r2 < (unsigned)nb) srcs[atomicAdd(&cur[r2], 1)] = src[e + 2];
        if (r3 < (unsigned)nb) srcs[atomicAdd(&cur[r3], 1)] = src[e + 3];
    }
    if (threadIdx.x == 0)
        for (int t = e1 & ~3; t < e1; ++t) {
            unsigned rel = (unsigned)(dst[t] - lo);
            if (rel < (unsigned)nb) srcs[atomicAdd(&cur[rel], 1)] = src[t];
        }
}

// ---- merged pack: T0 = bf16(x); Ys0 = bf16(dis*x); pad rows; Wt transpose ----
__global__ void k_pack(const float* __restrict__ x, const float* __restrict__ dis,
                       const float* __restrict__ W,
                       unsigned short* __restrict__ tb0, unsigned short* __restrict__ ysA,
                       unsigned short* __restrict__ ysB, unsigned short* __restrict__ wt,
                       int N, int K) {
    int t = blockIdx.x * blockDim.x + threadIdx.x;
    int nys = (N + 1) * 32;
    if (t < nys) {
        int row = t >> 5, p = t & 31;
        size_t o = ((size_t)row << 6) + (p << 1);
        if (row == N) {
            *(unsigned*)(ysA + o) = 0;
            *(unsigned*)(ysB + o) = 0;
            return;
        }
        float2 v = *reinterpret_cast<const float2*>(x + o);
        float dv = dis[row];
        *(unsigned*)(tb0 + o) = (unsigned)f2bf(v.x) | ((unsigned)f2bf(v.y) << 16);
        *(unsigned*)(ysA + o) = (unsigned)f2bf(v.x * dv) | ((unsigned)f2bf(v.y * dv) << 16);
    } else {
        int u = t - nys;
        if (u < K * 4096) {
            float v = W[u];
            int k = u >> 12;
            int r = u & 4095;
            int i = r >> 6;
            int j = r & 63;
            wt[(size_t)j * (K * 64) + (k << 6) + i] = f2bf(v);
        }
    }
}

static __device__ __forceinline__ void addrow(float* acc, uint4 t) {
    acc[0] += __uint_as_float(t.x << 16);
    acc[1] += __uint_as_float(t.x & 0xffff0000u);
    acc[2] += __uint_as_float(t.y << 16);
    acc[3] += __uint_as_float(t.y & 0xffff0000u);
    acc[4] += __uint_as_float(t.z << 16);
    acc[5] += __uint_as_float(t.z & 0xffff0000u);
    acc[6] += __uint_as_float(t.w << 16);
    acc[7] += __uint_as_float(t.w & 0xffff0000u);
}

// ---- Chebyshev propagation, slot-per-node, 8 edges in flight per slot ----
__global__ __launch_bounds__(256) void k_prop(
        const unsigned short* __restrict__ Ysin,
        const unsigned short* __restrict__ Tm2,
        unsigned short* __restrict__ Tout,
        unsigned short* __restrict__ Ysout,
        const int* __restrict__ rowptr, const int* __restrict__ srcs,
        const float* __restrict__ dis,
        int N, int E, float scale, float beta, int wys) {
    int gt = blockIdx.x * blockDim.x + threadIdx.x;
    int wave0 = (gt >> 6) << 3;          // first node of this wave
    int lane = gt & 63;
    int g = lane >> 3;                   // slot -> node wave0+g
    int i = lane & 7;                    // feature octet
    int node = wave0 + g;
    bool live = node < N;
    int rs = 0, deg = 0;
    if (live) {
        rs = rowptr[node];
        deg = rowptr[node + 1] - rs;
    }
    int wmax = deg;
#pragma unroll
    for (int m = 8; m <= 32; m <<= 1) {
        int o = __shfl_xor(wmax, m);
        wmax = o > wmax ? o : wmax;
    }
    float acc[8];
#pragma unroll
    for (int j = 0; j < 8; ++j) acc[j] = 0.f;
    for (int e = 0; e < wmax; e += 8) {
        int b = rs + e;
        int s[8];
#pragma unroll
        for (int q = 0; q < 8; ++q)
            s[q] = (e + q < deg) ? srcs[min(b + q, E - 1)] : N;
        uint4 t[8];
#pragma unroll
        for (int q = 0; q < 8; ++q)
            t[q] = *reinterpret_cast<const uint4*>(Ysin + ((size_t)s[q] << 6) + (i << 3));
#pragma unroll
        for (int q = 0; q < 8; ++q) addrow(acc, t[q]);
    }
    if (live) {
        float dv = dis[node];
        float sc = -scale * dv;
        size_t base = ((size_t)node << 6) + (i << 3);
        float r[8];
#pragma unroll
        for (int j = 0; j < 8; ++j) r[j] = sc * acc[j];
        if (beta != 0.f) {
            uint4 pv = *reinterpret_cast<const uint4*>(Tm2 + base);
            r[0] = fmaf(beta, __uint_as_float(pv.x << 16), r[0]);
            r[1] = fmaf(beta, __uint_as_float(pv.x & 0xffff0000u), r[1]);
            r[2] = fmaf(beta, __uint_as_float(pv.y << 16), r[2]);
            r[3] = fmaf(beta, __uint_as_float(pv.y & 0xffff0000u), r[3]);
            r[4] = fmaf(beta, __uint_as_float(pv.z << 16), r[4]);
            r[5] = fmaf(beta, __uint_as_float(pv.z & 0xffff0000u), r[5]);
            r[6] = fmaf(beta, __uint_as_float(pv.w << 16), r[6]);
            r[7] = fmaf(beta, __uint_as_float(pv.w & 0xffff0000u), r[7]);
        }
        uint4 ov;
        ov.x = (unsigned)f2bf(r[0]) | ((unsigned)f2bf(r[1]) << 16);
        ov.y = (unsigned)f2bf(r[2]) | ((unsigned)f2bf(r[3]) << 16);
        ov.z = (unsigned)f2bf(r[4]) | ((unsigned)f2bf(r[5]) << 16);
        ov.w = (unsigned)f2bf(r[6]) | ((unsigned)f2bf(r[7]) << 16);
        *reinterpret_cast<uint4*>(Tout + base) = ov;
        if (wys) {
            uint4 yv;
            yv.x = (unsigned)f2bf(r[0] * dv) | ((unsigned)f2bf(r[1] * dv) << 16);
            yv.y = (unsigned)f2bf(r[2] * dv) | ((unsigned)f2bf(r[3] * dv) << 16);
            yv.z = (unsigned)f2bf(r[4] * dv) | ((unsigned)f2bf(r[5] * dv) << 16);
            yv.w = (unsigned)f2bf(r[6] * dv) | ((unsigned)f2bf(r[7] * dv) << 16);
            *reinterpret_cast<uint4*>(Ysout + base) = yv;
        }
    }
}

// ---- out = relu( sum_k T_k @ W_k + bias ) via D = W^T . T^T (MFMA 16x16x32 bf16)
// B-tile staged via async global_load_lds (16 wave-instrs, all in flight, zero
// VGPR cost) -> ds_read_b128 fragments. XOR swizzle (seg ^ node&7), applied on
// the per-lane *global* source address (LDS dest must stay wave-uniform+lane*16),
// makes fragment reads 2-way-bank-aliased (free). R8/R9 showed register-level
// MLP is compiler-defeated (VGPR pinned at 44, loads fully serialized).
template <int KS>
__global__ __launch_bounds__(256) void k_gemm(const unsigned short* __restrict__ tb,
                                              const unsigned short* __restrict__ wt,
                                              const float* __restrict__ bias,
                                              float* __restrict__ out,
                                              int N, int NF) {
    constexpr int NB = KS / 2;              // 64-wide k-buffers per tile
    __shared__ unsigned short lds[KS * 512];  // NB * 2 KB
    int lane = threadIdx.x & 63;
    int w = threadIdx.x >> 6;
    int l16 = lane & 15;
    int quad = lane >> 4;
    const int KI = KS * 32;

    s16x8 afr[KS];
    {
        const unsigned short* wrow = wt + (size_t)(w * 16 + l16) * KI + quad * 8;
#pragma unroll
        for (int ks = 0; ks < KS; ++ks)
            afr[ks] = *reinterpret_cast<const s16x8*>(wrow + ks * 32);
    }
    f32x4 bias4 = *reinterpret_cast<const f32x4*>(bias + w * 16 + quad * 4);

    int ntiles = N >> 4;
    for (int t = blockIdx.x; t < ntiles; t += gridDim.x) {
        // ---- stage B tile: NB chunks of 2 KB; 2 instrs/chunk, round-robin over waves
        const char* tilebase = (const char*)tb + (size_t)t * 2048;  // t*16*64 elems *2B
#pragma unroll
        for (int inst = 0; inst < 2 * NB; ++inst) {
            if ((inst & 3) != w) continue;
            int kbuf = inst >> 1;
            int j = inst & 1;
            int p = j * 64 + lane;          // physical 16B slot within kbuf chunk
            int nrow = p >> 3;              // node 0..15
            int s = (p & 7) ^ (nrow & 7);   // logical seg for this physical slot
            const char* g = tilebase + (size_t)kbuf * NF * 2 + nrow * 128 + s * 16;
            __builtin_amdgcn_global_load_lds(
                (const __attribute__((address_space(1))) unsigned int*)g,
                (__attribute__((address_space(3))) unsigned int*)(lds + inst * 512),
                16, 0, 0);
        }
        __syncthreads();   // drains vmcnt (incl. load_lds) + barrier
        // ---- fragments from LDS + MFMA
        f32x4 acc = {0.f, 0.f, 0.f, 0.f};
#pragma unroll
        for (int ks = 0; ks < KS; ++ks) {
            int kbuf = ks >> 1, half = ks & 1;
            int sph = (half * 4 + quad) ^ (l16 & 7);
            s16x8 bf = *reinterpret_cast<const s16x8*>(
                lds + kbuf * 1024 + l16 * 64 + sph * 8);
            acc = __builtin_amdgcn_mfma_f32_16x16x32_bf16(afr[ks], bf, acc, 0, 0, 0);
        }
        float* orow = out + (size_t)(t * 16 + l16) * 64 + w * 16 + quad * 4;
        f32x4 r;
#pragma unroll
        for (int q = 0; q < 4; ++q) {
            float v = acc[q] + bias4[q];
            r[q] = v > 0.f ? v : 0.f;
        }
        *reinterpret_cast<f32x4*>(orow) = r;
        __syncthreads();   // protect LDS before next tile's staging
    }
}

extern "C" void kernel_launch(void* const* d_in, const int* in_sizes, int n_in,
                              void* d_out, int out_size, void* d_ws, size_t ws_size,
                              hipStream_t stream) {
    const float* x    = (const float*)d_in[0];
    const int*   eidx = (const int*)d_in[1];
    const float* W    = (const float*)d_in[2];
    const float* bias = (const float*)d_in[3];
    float* out = (float*)d_out;

    const int NF = in_sizes[0];       // N*64
    const int N  = NF / 64;
    const int E  = in_sizes[1] / 2;
    const int K  = in_sizes[2] / 4096;

    const int* src = eidx;
    const int* dst = eidx + E;

    char* ws = (char*)d_ws;
    size_t off = 0;
    auto alloc = [&](size_t bytes) -> char* {
        char* p = ws + off;
        off = (off + bytes + 255) & ~(size_t)255;
        return p;
    };
    unsigned short* Tb = (unsigned short*)alloc((size_t)K * NF * 2);   // bf16 T_0..T_{K-1}
    unsigned short* Ys[2];
    Ys[0] = (unsigned short*)alloc((size_t)(N + 1) * 64 * 2);
    Ys[1] = (unsigned short*)alloc((size_t)(N + 1) * 64 * 2);
    unsigned short* Wt = (unsigned short*)alloc((size_t)64 * K * 64 * 2);
    int*   srcs   = (int*)alloc((size_t)E * 4);
    int*   rowptr = (int*)alloc((size_t)(N + 1) * 4);
    int*   cnt    = (int*)alloc((size_t)N * 4);
    unsigned short* partials = (unsigned short*)alloc((size_t)2 * HC * N * 2);
    int*   cbase  = (int*)alloc((size_t)HC * N * 4);
    float* dis  = (float*)alloc((size_t)N * 4);
    int*   bsum = (int*)alloc(1024);
    int*   boff = (int*)alloc(1024);
    (void)ws_size; (void)n_in; (void)out_size;

    int HR = (N + RBH - 1) / RBH;   // 16
    int SR = (N + RBS - 1) / RBS;   // 32
    const unsigned short* pdst = partials + (size_t)HC * N;

    k_hist<<<2 * HR * HC, 256, 0, stream>>>(eidx, partials, N, E, HR);
    k_reduce<<<(N + 255) / 256, 256, 0, stream>>>(partials, dis, cnt, N);
    int nb = (N + 1023) / 1024;
    k_scan1<<<nb, 1024, 0, stream>>>(cnt, rowptr, bsum, N);
    k_scan2<<<1, 64, 0, stream>>>(bsum, boff, nb, rowptr, N);
    k_scan3<<<nb, 1024, 0, stream>>>(cnt, boff, rowptr, pdst, cbase, N);
    k_scatter<<<SR * HC, 256, 0, stream>>>(src, dst, cbase, srcs, N, E);
    int packn = (N + 1) * 32 + K * 4096;
    k_pack<<<(packn + 255) / 256, 256, 0, stream>>>(x, dis, W, Tb, Ys[0], Ys[1], Wt, N, K);

    // prop grid: 8 nodes per wave
    int waves = (N + 7) / 8;
    int pblocks = (waves * 64 + 255) / 256;
    for (int p = 1; p < K; ++p) {
        float scale = (p == 1) ? 1.f : 2.f;
        float beta  = (p == 1) ? 0.f : -1.f;
        const unsigned short* Tm2 = Tb + (size_t)(p >= 2 ? p - 2 : 0) * NF;
        k_prop<<<pblocks, 256, 0, stream>>>(
            Ys[(p - 1) & 1], Tm2, Tb + (size_t)p * NF, Ys[p & 1],
            rowptr, srcs, dis, N, E, scale, beta, p < K - 1 ? 1 : 0);
    }

    if (K == 8)      k_gemm<16><<<1024, 256, 0, stream>>>(Tb, Wt, bias, out, N, NF);
    else if (K == 4) k_gemm<8><<<1024, 256, 0, stream>>>(Tb, Wt, bias, out, N, NF);
    else if (K == 2) k_gemm<4><<<1024, 256, 0, stream>>>(Tb, Wt, bias, out, N, NF);
    else if (K == 1) k_gemm<2><<<1024, 256, 0, stream>>>(Tb, Wt, bias, out, N, NF);
}